// Round 1
// baseline (499.379 us; speedup 1.0000x reference)
//
#include <hip/hip_runtime.h>
#include <hip/hip_bf16.h>
#include <stdint.h>

typedef unsigned short u16;
typedef __bf16 bf16x8 __attribute__((ext_vector_type(8)));
typedef float f32x4 __attribute__((ext_vector_type(4)));
typedef float f32x8 __attribute__((ext_vector_type(8)));

#define BM 128
#define BN 128
#define BK 64

struct SegArgs {
  const u16* W[4];
  const float* b[4];
  void* out[4];
  int act[4];      // 0=none 1=sigmoid 2=tanh 3=relu
  int bf16out[4];  // 1 = store bf16, 0 = store fp32
};

__device__ __forceinline__ float bf2f(u16 u) {
  union { unsigned int i; float f; } v; v.i = ((unsigned int)u) << 16; return v.f;
}
__device__ __forceinline__ u16 f2bf(float f) {
  union { float f; unsigned int i; } v; v.f = f;
  return (u16)((v.i + 0x7fffu + ((v.i >> 16) & 1u)) >> 16);
}
__device__ __forceinline__ uint4 cvt8(f32x8 v) {
  uint4 r;
  r.x = (unsigned)f2bf(v[0]) | ((unsigned)f2bf(v[1]) << 16);
  r.y = (unsigned)f2bf(v[2]) | ((unsigned)f2bf(v[3]) << 16);
  r.z = (unsigned)f2bf(v[4]) | ((unsigned)f2bf(v[5]) << 16);
  r.w = (unsigned)f2bf(v[6]) | ((unsigned)f2bf(v[7]) << 16);
  return r;
}
__device__ __forceinline__ float actf(float x, int act) {
  if (act == 1) return 1.0f / (1.0f + __expf(-x));
  if (act == 2) {
    float xc = fminf(fmaxf(x, -15.0f), 15.0f);
    float e = __expf(2.0f * xc);
    return (e - 1.0f) / (e + 1.0f);
  }
  if (act == 3) return fmaxf(x, 0.0f);
  return x;
}

// ---- bulk fp32 -> bf16 convert; chunk = 2M elements, blockIdx.y = chunk ----
struct CvtArgs { const float* src[10]; u16* dst[10]; };
__global__ void cvt_f2b(CvtArgs a) {
  const float* s = a.src[blockIdx.y];
  u16* d = a.dst[blockIdx.y];
  int i0 = (blockIdx.x * 256 + threadIdx.x) * 8;
  f32x8 v = *(const f32x8*)(s + i0);
  *(uint4*)(d + i0) = cvt8(v);
}

// ============================================================================
// gemm_bt2: 256x256 tile, BK=32, 8 waves (2M x 4N), ring-of-4 LDS buffers
// (128 KB), counted-vmcnt pipeline (T3+T4), raw s_barrier (no vmcnt(0) drain),
// setprio around MFMA cluster (T5), XOR bank swizzle (T2).
//
// Pipeline invariant (per wave, 4 global_load_lds per K-tile):
//   prologue stages tiles 0,1,2 (12 loads in flight).
//   iter t: s_waitcnt vmcnt(8)  -> tile t landed, tiles t+1,t+2 in flight
//           s_barrier            -> ALL waves' tile-t loads landed; all waves
//                                   finished iter t-1 ds_reads (reads complete
//                                   before their MFMAs issue, which precede the
//                                   wave's barrier) => buffer (t-1)&3 is free
//           STAGE(t+3) into buffer (t+3)&3 == (t-1)&3
//           ds_read frags of tile t, MFMA (compiler inserts fine lgkmcnt)
//   tail: vmcnt(4) at t=NT-2, vmcnt(0) at t=NT-1.
// ============================================================================
#define G2M 256
#define G2K 32

__global__ __launch_bounds__(512, 2) void gemm_bt2(
    const u16* __restrict__ A0, const u16* __restrict__ A1, int KA0, int K,
    SegArgs segs, int tileShift, int ldOut)
{
  // 4 ring buffers x (A 256x32 bf16 = 8192 u16, B same) = 131072 B
  __shared__ u16 smem[4 * 16384];

  const int tid  = threadIdx.x;
  const int lane = tid & 63;
  const int wave = tid >> 6;
  const int wm = wave & 1, wn = wave >> 1;       // 2 x 4 wave grid
  const int mBlock  = blockIdx.x * G2M;
  const int seg     = blockIdx.y >> tileShift;
  const int nTile   = blockIdx.y & ((1 << tileShift) - 1);
  const int colBase = nTile * G2M;
  const u16* Wp = segs.W[seg];
  const int NT = K / G2K;

  // stage K-tile kt into ring buffer (kt&3).  Linear LDS dest (wave-uniform
  // base + lane*16); bank swizzle applied by permuting the GLOBAL source
  // chunk: granule (row, p) holds data chunk c = p ^ ((row>>1)&3).
  auto STAGE = [&](int kt) {
    int kb = kt * G2K;
    const u16* Aseg; int ka, ldA;
    if (kb < KA0) { Aseg = A0; ka = kb;       ldA = KA0; }
    else          { Aseg = A1; ka = kb - KA0; ldA = K - KA0; }
    u16* base = &smem[(kt & 3) * 16384];
#pragma unroll
    for (int it = 0; it < 2; ++it) {
      int g   = it * 512 + tid;                  // 16B granule, 0..1023
      int row = g >> 2;                          // 0..255
      int c   = (g & 3) ^ ((row >> 1) & 3);      // inverse swizzle on source
      const u16* srcA = Aseg + (size_t)(mBlock  + row) * (size_t)ldA + (ka + c * 8);
      const u16* srcB = Wp   + (size_t)(colBase + row) * (size_t)K   + (kb + c * 8);
      u16* dA = base +        (it * 512 + wave * 64) * 8;
      u16* dB = base + 8192 + (it * 512 + wave * 64) * 8;
      __builtin_amdgcn_global_load_lds((void*)srcA, (void*)dA, 16, 0, 0);
      __builtin_amdgcn_global_load_lds((void*)srcB, (void*)dB, 16, 0, 0);
    }
  };

  const f32x4 zero = {0.f, 0.f, 0.f, 0.f};
  f32x4 acc[8][4];
#pragma unroll
  for (int m = 0; m < 8; ++m)
#pragma unroll
    for (int n = 0; n < 4; ++n) acc[m][n] = zero;

  STAGE(0); STAGE(1); STAGE(2);                  // 12 loads/wave in flight

  for (int t = 0; t < NT; ++t) {
    if      (t + 3 <= NT) asm volatile("s_waitcnt vmcnt(8)" ::: "memory");
    else if (t + 2 <= NT) asm volatile("s_waitcnt vmcnt(4)" ::: "memory");
    else                  asm volatile("s_waitcnt vmcnt(0)" ::: "memory");
    __builtin_amdgcn_sched_barrier(0);
    __builtin_amdgcn_s_barrier();                // raw: keeps vmem in flight
    __builtin_amdgcn_sched_barrier(0);

    if (t + 3 < NT) STAGE(t + 3);

    const u16* Ab = &smem[(t & 3) * 16384];
    const u16* Bb = Ab + 8192;
    const int q = lane >> 4;                     // k-chunk of this lane group
    bf16x8 af[8], bfr[4];
#pragma unroll
    for (int m = 0; m < 8; ++m) {
      int r = wm * 128 + m * 16 + (lane & 15);
      int p = q ^ ((r >> 1) & 3);
      af[m] = *(const bf16x8*)(Ab + (r * 4 + p) * 8);
    }
#pragma unroll
    for (int n = 0; n < 4; ++n) {
      int r = wn * 64 + n * 16 + (lane & 15);
      int p = q ^ ((r >> 1) & 3);
      bfr[n] = *(const bf16x8*)(Bb + (r * 4 + p) * 8);
    }
    __builtin_amdgcn_s_setprio(1);
#pragma unroll
    for (int m = 0; m < 8; ++m)
#pragma unroll
      for (int n = 0; n < 4; ++n)
        acc[m][n] = __builtin_amdgcn_mfma_f32_16x16x32_bf16(af[m], bfr[n], acc[m][n], 0, 0, 0);
    __builtin_amdgcn_s_setprio(0);
  }

  // epilogue: +bias, activation.  C/D map: col=lane&15, row=(lane>>4)*4+r
  const float* bp = segs.b[seg];
  const int act  = segs.act[seg];
  const int isBf = segs.bf16out[seg];
  u16*   opb = (u16*)segs.out[seg];
  float* opf = (float*)segs.out[seg];
  const int q4 = (lane >> 4) * 4;
  const int cl = lane & 15;
#pragma unroll
  for (int n = 0; n < 4; ++n) {
    int col = colBase + wn * 64 + n * 16 + cl;
    float bv = bp[col];
#pragma unroll
    for (int m = 0; m < 8; ++m) {
      int row = mBlock + wm * 128 + m * 16 + q4;
#pragma unroll
      for (int r = 0; r < 4; ++r) {
        float v = actf(acc[m][n][r] + bv, act);
        size_t idx = (size_t)(row + r) * (size_t)ldOut + col;
        if (isBf) opb[idx] = f2bf(v); else opf[idx] = v;
      }
    }
  }
}

// ---- old 128x128 m97-structure kernel: kept for the two head GEMMs, whose
// N (2048 / 1024) would leave the chip under-occupied at 256^2 tiles ----
__global__ __launch_bounds__(256, 2) void gemm_bt(
    const u16* __restrict__ A0, const u16* __restrict__ A1, int KA0, int K,
    SegArgs segs, int tileShift, int ldOut)
{
  __shared__ u16 As[BM * BK];
  __shared__ u16 Bs[BN * BK];

  const int tid  = threadIdx.x;
  const int lane = tid & 63;
  const int wave = tid >> 6;
  const int mBlock = blockIdx.x * BM;
  const int seg   = blockIdx.y >> tileShift;
  const int nTile = blockIdx.y & ((1 << tileShift) - 1);

  const u16* Wp = segs.W[seg];
  const int wm = wave & 1, wn = wave >> 1;

  const f32x4 zero = {0.f, 0.f, 0.f, 0.f};
  f32x4 acc[4][4];
#pragma unroll
  for (int i = 0; i < 4; ++i)
#pragma unroll
    for (int j = 0; j < 4; ++j) acc[i][j] = zero;

  for (int kb = 0; kb < K; kb += BK) {
    const u16* Aseg; int ka; int ldA;
    if (kb < KA0) { Aseg = A0; ka = kb;       ldA = KA0; }
    else          { Aseg = A1; ka = kb - KA0; ldA = K - KA0; }

#pragma unroll
    for (int it = 0; it < 4; ++it) {
      int s = it * 256 + tid;
      int m = s >> 3;
      int p = s & 7;
      int kc = p ^ (m & 7);
      const u16* srcA = Aseg + (size_t)(mBlock + m) * (size_t)ldA + (ka + kc * 8);
      const u16* srcB = Wp + (size_t)(nTile * BN + m) * (size_t)K + (kb + kc * 8);
      u16* dA = &As[(it * 256 + wave * 64) * 8];
      u16* dB = &Bs[(it * 256 + wave * 64) * 8];
      __builtin_amdgcn_global_load_lds((void*)srcA, (void*)dA, 16, 0, 0);
      __builtin_amdgcn_global_load_lds((void*)srcB, (void*)dB, 16, 0, 0);
    }
    __syncthreads();

#pragma unroll
    for (int ko = 0; ko < 2; ++ko) {
      bf16x8 af[4], bfr[4];
      int kcb = ko * 4 + (lane >> 4);
      int p = kcb ^ (lane & 7);
#pragma unroll
      for (int t = 0; t < 4; ++t) {
        int ml = wm * 64 + t * 16 + (lane & 15);
        af[t]  = *(const bf16x8*)&As[(ml * 8 + p) * 8];
        int nl = wn * 64 + t * 16 + (lane & 15);
        bfr[t] = *(const bf16x8*)&Bs[(nl * 8 + p) * 8];
      }
#pragma unroll
      for (int tm = 0; tm < 4; ++tm)
#pragma unroll
        for (int tn = 0; tn < 4; ++tn)
          acc[tm][tn] = __builtin_amdgcn_mfma_f32_16x16x32_bf16(af[tm], bfr[tn], acc[tm][tn], 0, 0, 0);
    }
    __syncthreads();
  }

  const float* bp = segs.b[seg];
  const int act = segs.act[seg];
  const int isBf = segs.bf16out[seg];
  u16*   opb = (u16*)segs.out[seg];
  float* opf = (float*)segs.out[seg];
  const int q  = lane >> 4;
  const int cl = lane & 15;
#pragma unroll
  for (int tn = 0; tn < 4; ++tn) {
    int col = nTile * BN + wn * 64 + tn * 16 + cl;
    float bv = bp[col];
#pragma unroll
    for (int tm = 0; tm < 4; ++tm) {
      int row = mBlock + wm * 64 + tm * 16 + q * 4;
#pragma unroll
      for (int r = 0; r < 4; ++r) {
        float v = actf(acc[tm][tn][r] + bv, act);
        size_t idx = (size_t)(row + r) * (size_t)ldOut + col;
        if (isBf) opb[idx] = f2bf(v); else opf[idx] = v;
      }
    }
  }
}

// combine gates (bf16): c_new = f*c0 + cand*i ; h_new = o*tanh(cand).
__global__ void lstm_ew(const u16* __restrict__ gates, const float* __restrict__ cold,
                        float* __restrict__ hout, float* __restrict__ cout,
                        u16* __restrict__ hb, int n)
{
  int i0 = (blockIdx.x * blockDim.x + threadIdx.x) * 8;
  if (i0 >= n) return;
  union U { uint4 v; u16 u[8]; };
  U F, I, C, O;
  F.v = *(const uint4*)(gates + i0);
  I.v = *(const uint4*)(gates + (size_t)n + i0);
  C.v = *(const uint4*)(gates + 2 * (size_t)n + i0);
  O.v = *(const uint4*)(gates + 3 * (size_t)n + i0);
  f32x8 c0v = *(const f32x8*)(cold + i0);
  f32x8 H, CN;
#pragma unroll
  for (int j = 0; j < 8; ++j) {
    float f  = bf2f(F.u[j]);
    float ig = bf2f(I.u[j]);
    float cd = bf2f(C.u[j]);   // already tanh'd, in (-1,1)
    float o  = bf2f(O.u[j]);
    float cn = f * c0v[j] + cd * ig;
    float e  = __expf(2.0f * cd);
    float th = (e - 1.0f) / (e + 1.0f);
    H[j]  = o * th;            // faithful double-tanh
    CN[j] = cn;
  }
  *(f32x8*)(hout + i0) = H;
  *(f32x8*)(cout + i0) = CN;
  *(uint4*)(hb + i0) = cvt8(H);
}

extern "C" void kernel_launch(void* const* d_in, const int* in_sizes, int n_in,
                              void* d_out, int out_size, void* d_ws, size_t ws_size,
                              hipStream_t stream)
{
  const size_t P   = 4096ull * 1024ull;  // 4,194,304 elements
  const size_t C2M = 2097152ull;         // cvt chunk = 2M elements

  const float* X   = (const float*)d_in[0];
  const float* h1i = (const float*)d_in[1];
  const float* h2i = (const float*)d_in[2];
  const float* c1i = (const float*)d_in[3];
  const float* c2i = (const float*)d_in[4];
  const float* Wf1 = (const float*)d_in[5];  const float* bf1_ = (const float*)d_in[6];
  const float* Wi1 = (const float*)d_in[7];  const float* bi1_ = (const float*)d_in[8];
  const float* Wc1 = (const float*)d_in[9];  const float* bc1_ = (const float*)d_in[10];
  const float* Wo1 = (const float*)d_in[11]; const float* bo1_ = (const float*)d_in[12];
  const float* Wf2 = (const float*)d_in[13]; const float* bf2_ = (const float*)d_in[14];
  const float* Wi2 = (const float*)d_in[15]; const float* bi2_ = (const float*)d_in[16];
  const float* Wc2 = (const float*)d_in[17]; const float* bc2_ = (const float*)d_in[18];
  const float* Wo2 = (const float*)d_in[19]; const float* bo2_ = (const float*)d_in[20];
  const float* W3  = (const float*)d_in[21]; const float* b3_  = (const float*)d_in[22];
  const float* W4  = (const float*)d_in[23]; const float* b4_  = (const float*)d_in[24];

  float* out = (float*)d_out;     // fp32 outputs (reference dtype)
  float* h1  = out + P;
  float* h2  = out + 2 * P;
  float* c1  = out + 3 * P;
  float* c2  = out + 4 * P;

  // ws layout (80 MB), phase-aliased:
  //  D @  0MB (32): gates bf16          (GEMM1->ew1, GEMM2->ew2)
  //  A @ 32MB (16): W1b -> W2b -> out3b
  //  B @ 48MB ( 8): Xb  -> h2ib
  //  Cg@ 56MB ( 8): h1ib -> h2b
  //  E @ 64MB ( 8): h1b
  //  F @ 72MB ( 8): W3b (4) + W4b (4)
  char* ws = (char*)d_ws;
  u16* gates = (u16*)ws;
  u16* Areg  = (u16*)(ws + (32ull << 20));
  u16* Breg  = (u16*)(ws + (48ull << 20));
  u16* Creg  = (u16*)(ws + (56ull << 20));
  u16* Ereg  = (u16*)(ws + (64ull << 20));
  u16* Freg  = (u16*)(ws + (72ull << 20));

  dim3 blk(256, 1, 1);
  dim3 blk2(512, 1, 1);

  // ---- cvtA: W1 gates, X, h1i, W3, W4 -> bf16 ----
  CvtArgs ca;
  ca.src[0]=Wf1;        ca.dst[0]=Areg;
  ca.src[1]=Wi1;        ca.dst[1]=Areg + C2M;
  ca.src[2]=Wc1;        ca.dst[2]=Areg + 2*C2M;
  ca.src[3]=Wo1;        ca.dst[3]=Areg + 3*C2M;
  ca.src[4]=X;          ca.dst[4]=Breg;
  ca.src[5]=X + C2M;    ca.dst[5]=Breg + C2M;
  ca.src[6]=h1i;        ca.dst[6]=Creg;
  ca.src[7]=h1i + C2M;  ca.dst[7]=Creg + C2M;
  ca.src[8]=W3;         ca.dst[8]=Freg;
  ca.src[9]=W4;         ca.dst[9]=Freg + C2M;
  cvt_f2b<<<dim3(1024, 10, 1), blk, 0, stream>>>(ca);

  // ---- LSTM layer 1: fused 4-gate GEMM (N=4096, K=2048), 256^2 pipeline ----
  SegArgs s1;
  s1.W[0]=Areg; s1.W[1]=Areg+C2M; s1.W[2]=Areg+2*C2M; s1.W[3]=Areg+3*C2M;
  s1.b[0]=bf1_; s1.b[1]=bi1_; s1.b[2]=bc1_; s1.b[3]=bo1_;
  s1.out[0]=gates; s1.out[1]=gates+P; s1.out[2]=gates+2*P; s1.out[3]=gates+3*P;
  s1.act[0]=1; s1.act[1]=1; s1.act[2]=2; s1.act[3]=1;
  s1.bf16out[0]=s1.bf16out[1]=s1.bf16out[2]=s1.bf16out[3]=1;
  gemm_bt2<<<dim3(16,16,1), blk2, 0, stream>>>(Breg, Creg, 1024, 2048, s1, 2, 1024);
  lstm_ew<<<dim3(2048,1,1), blk, 0, stream>>>(gates, c1i, h1, c1, Ereg, (int)P);

  // ---- cvtB: W2 gates, h2i -> bf16 (overwrite A/B regions) ----
  CvtArgs cb;
  cb.src[0]=Wf2;        cb.dst[0]=Areg;
  cb.src[1]=Wi2;        cb.dst[1]=Areg + C2M;
  cb.src[2]=Wc2;        cb.dst[2]=Areg + 2*C2M;
  cb.src[3]=Wo2;        cb.dst[3]=Areg + 3*C2M;
  cb.src[4]=h2i;        cb.dst[4]=Breg;
  cb.src[5]=h2i + C2M;  cb.dst[5]=Breg + C2M;
  cvt_f2b<<<dim3(1024, 6, 1), blk, 0, stream>>>(cb);

  // ---- LSTM layer 2: A = [h1b | h2ib], 256^2 pipeline ----
  SegArgs s2 = s1;
  s2.b[0]=bf2_; s2.b[1]=bi2_; s2.b[2]=bc2_; s2.b[3]=bo2_;
  gemm_bt2<<<dim3(16,16,1), blk2, 0, stream>>>(Ereg, Breg, 1024, 2048, s2, 2, 1024);
  lstm_ew<<<dim3(2048,1,1), blk, 0, stream>>>(gates, c2i, h2, c2, Creg, (int)P);

  // ---- head: out3b = relu(h2b @ W3^T + b3), N=2048, K=1024, bf16 out -> A ----
  SegArgs s3;
  for (int g = 0; g < 4; ++g) { s3.W[g]=Freg; s3.b[g]=b3_; s3.out[g]=Areg; s3.act[g]=3; s3.bf16out[g]=1; }
  gemm_bt<<<dim3(32,16,1), blk, 0, stream>>>(Creg, (const u16*)nullptr, 1024, 1024, s3, 4, 2048);

  // ---- head: out = out3b @ W4^T + b4, N=1024, K=2048, fp32 out ----
  SegArgs s4;
  for (int g = 0; g < 4; ++g) { s4.W[g]=Freg+C2M; s4.b[g]=b4_; s4.out[g]=out; s4.act[g]=0; s4.bf16out[g]=0; }
  gemm_bt<<<dim3(32,8,1), blk, 0, stream>>>(Areg, (const u16*)nullptr, 2048, 2048, s4, 3, 1024);
}

// Round 2
// 497.429 us; speedup vs baseline: 1.0039x; 1.0039x over previous
//
#include <hip/hip_runtime.h>
#include <hip/hip_bf16.h>
#include <stdint.h>

typedef unsigned short u16;
typedef __bf16 bf16x8 __attribute__((ext_vector_type(8)));
typedef float f32x4 __attribute__((ext_vector_type(4)));
typedef float f32x8 __attribute__((ext_vector_type(8)));

#define BM 128
#define BN 128
#define BK 64

struct SegArgs {
  const u16* W[4];
  const float* b[4];
  void* out[4];
  int act[4];      // 0=none 1=sigmoid 2=tanh 3=relu
  int bf16out[4];  // 1 = store bf16, 0 = store fp32
};

__device__ __forceinline__ float bf2f(u16 u) {
  union { unsigned int i; float f; } v; v.i = ((unsigned int)u) << 16; return v.f;
}
__device__ __forceinline__ u16 f2bf(float f) {
  union { float f; unsigned int i; } v; v.f = f;
  return (u16)((v.i + 0x7fffu + ((v.i >> 16) & 1u)) >> 16);
}
__device__ __forceinline__ uint4 cvt8(f32x8 v) {
  uint4 r;
  r.x = (unsigned)f2bf(v[0]) | ((unsigned)f2bf(v[1]) << 16);
  r.y = (unsigned)f2bf(v[2]) | ((unsigned)f2bf(v[3]) << 16);
  r.z = (unsigned)f2bf(v[4]) | ((unsigned)f2bf(v[5]) << 16);
  r.w = (unsigned)f2bf(v[6]) | ((unsigned)f2bf(v[7]) << 16);
  return r;
}
__device__ __forceinline__ float actf(float x, int act) {
  if (act == 1) return 1.0f / (1.0f + __expf(-x));
  if (act == 2) {
    float xc = fminf(fmaxf(x, -15.0f), 15.0f);
    float e = __expf(2.0f * xc);
    return (e - 1.0f) / (e + 1.0f);
  }
  if (act == 3) return fmaxf(x, 0.0f);
  return x;
}

// ---- bulk fp32 -> bf16 convert; chunk = 2M elements, blockIdx.y = chunk ----
struct CvtArgs { const float* src[10]; u16* dst[10]; };
__global__ void cvt_f2b(CvtArgs a) {
  const float* s = a.src[blockIdx.y];
  u16* d = a.dst[blockIdx.y];
  int i0 = (blockIdx.x * 256 + threadIdx.x) * 8;
  f32x8 v = *(const f32x8*)(s + i0);
  *(uint4*)(d + i0) = cvt8(v);
}

// ============================================================================
// gemm8p: the m201 8-phase 256^2 schedule in plain HIP.
// BM=BN=256, BK=64 per K-tile, 2 K-tiles per iteration, 8 waves (2M x 4N),
// 2 LDS buffers (tile parity), 128 KiB total.  Per phase:
//   {ds-read subtile || stage 1 half-tile (2 gload_lds)} -> barrier ->
//   lgkmcnt(0) -> setprio(1) -> 16 MFMA (2m x 4n quadrant, K=64) ->
//   setprio(0) -> barrier.
// vmcnt ONLY at phases 4 and 8, N=6 steady state (3 half-tiles in flight).
//
// Ledger (stages, 2 loads each, issue order; tile t0=2i buf0, t1=2i+1 buf1):
//   ph1: t1.A-hi | ph2: t0+2.B-lo | ph3: t0+2.B-hi | ph4: t0+2.A-lo
//   ph5: t0+2.A-hi | ph6: t1+2.B-lo | ph7: t1+2.B-hi | ph8: t1+2.A-lo
// vmcnt(6)@ph4 drains through ph1 (tile t1 complete before ph5 reads);
// vmcnt(6)@ph8 drains through ph5 (tile t0+2 complete before ph1' reads).
// Region-overwrite safety: each staged region's last ds_read completed
// before the previous phase's closing barrier (B read only at ph1/ph5 and
// reg-held; A rows read 32/phase; A half-tiles are the interleaved granule
// pairs {0-63,128-191} / {64-127,192-255} so 'A-lo' is fully read by ph2).
// Tail: last iteration's ph2..ph8 stages are skipped (tile >= NT), so the
// vmcnt switches to 0 there (steady-state 6 would under-drain).
// ============================================================================

#define FENCE  asm volatile("" ::: "memory")
#define SCHED0 __builtin_amdgcn_sched_barrier(0)

#define PH_SYNC do { \
  FENCE; SCHED0; \
  __builtin_amdgcn_s_barrier(); \
  asm volatile("s_waitcnt lgkmcnt(0)" ::: "memory"); \
  SCHED0; \
} while (0)

#define PH_SYNC_VM(NOTLAST) do { \
  FENCE; SCHED0; \
  if (NOTLAST) asm volatile("s_waitcnt vmcnt(6)" ::: "memory"); \
  else         asm volatile("s_waitcnt vmcnt(0)" ::: "memory"); \
  __builtin_amdgcn_s_barrier(); \
  asm volatile("s_waitcnt lgkmcnt(0)" ::: "memory"); \
  SCHED0; \
} while (0)

#define PH_END do { \
  SCHED0; FENCE; \
  __builtin_amdgcn_s_barrier(); \
  SCHED0; \
} while (0)

#define QUAD(MQ) do { \
  __builtin_amdgcn_s_setprio(1); \
  _Pragma("unroll") for (int kk = 0; kk < 2; ++kk) \
  _Pragma("unroll") for (int mi = 0; mi < 2; ++mi) \
  _Pragma("unroll") for (int n = 0; n < 4; ++n) \
    acc[(MQ) * 2 + mi][n] = __builtin_amdgcn_mfma_f32_16x16x32_bf16( \
        a2[mi][kk], bfr[n][kk], acc[(MQ) * 2 + mi][n], 0, 0, 0); \
  __builtin_amdgcn_s_setprio(0); \
} while (0)

__global__ __launch_bounds__(512, 2) void gemm8p(
    const u16* __restrict__ A0, const u16* __restrict__ A1, int KA0, int K,
    SegArgs segs, int tileShift, int ldOut)
{
  // 2 buffers x (A 256x64 bf16 = 16384 u16 + B same) = 131072 B
  __shared__ u16 smem[2 * 32768];

  const int tid  = threadIdx.x;
  const int lane = tid & 63;
  const int wave = tid >> 6;
  const int wm = wave & 1, wn = wave >> 1;       // 2M x 4N wave grid
  const int mBlock  = blockIdx.x * 256;
  const int seg     = blockIdx.y >> tileShift;
  const int nTile   = blockIdx.y & ((1 << tileShift) - 1);
  const int colBase = nTile * 256;
  const u16* Wp = segs.W[seg];
  const int NT  = K >> 6;                        // 64-wide K-tiles
  const int NIT = NT >> 1;

  // staging geometry: granule = 64 rows x 64 cols = 8 KB = 512 thr x 16 B.
  // source chunk is inverse-swizzled so LDS stays linear (slot s holds data
  // chunk c = s ^ (row & 7)); per-thread swizzled chunk is tid-constant.
  const int rowoff = tid >> 3;                   // row within granule
  const int csw    = (tid & 7) ^ (rowoff & 7);   // swizzled source chunk

  // which: 0 = B rows 0-127 | 1 = B rows 128-255
  //        2 = A rows {0-63, 128-191} | 3 = A rows {64-127, 192-255}
  auto STAGE = [&](int kt, int which) {
    if (kt >= NT) return;
    const int kb = kt << 6;
    u16* base = &smem[(kt & 1) * 32768];
    if (which < 2) {
      const int r0 = which << 7;
#pragma unroll
      for (int h = 0; h < 2; ++h) {
        const int rb = r0 + (h << 6);
        const u16* src = Wp + (size_t)(colBase + rb + rowoff) * (size_t)K + (kb + csw * 8);
        u16* dst = base + 16384 + rb * 64 + wave * 512;   // wave-uniform base
        __builtin_amdgcn_global_load_lds((void*)src, (void*)dst, 16, 0, 0);
      }
    } else {
      const u16* Aseg; int ka, ldA;
      if (kb < KA0) { Aseg = A0; ka = kb;       ldA = KA0; }
      else          { Aseg = A1; ka = kb - KA0; ldA = K - KA0; }
      const int r0 = (which & 1) << 6;           // 2 -> 0, 3 -> 64
#pragma unroll
      for (int h = 0; h < 2; ++h) {
        const int rb = r0 + (h << 7);            // +0 / +128
        const u16* src = Aseg + (size_t)(mBlock + rb + rowoff) * (size_t)ldA + (ka + csw * 8);
        u16* dst = base + rb * 64 + wave * 512;
        __builtin_amdgcn_global_load_lds((void*)src, (void*)dst, 16, 0, 0);
      }
    }
  };

  const int rl = lane & 15;
  const int qk = lane >> 4;

  auto LDA = [&](bf16x8 (&a2)[2][2], int bufb, int mq) {
#pragma unroll
    for (int mi = 0; mi < 2; ++mi) {
      const int r = wm * 128 + ((mq * 2 + mi) << 4) + rl;
      const int rowb = bufb + r * 64;
#pragma unroll
      for (int kk = 0; kk < 2; ++kk) {
        const int s = (qk + kk * 4) ^ (r & 7);
        a2[mi][kk] = *(const bf16x8*)&smem[rowb + s * 8];
      }
    }
  };
  auto LDBf = [&](bf16x8 (&b)[4][2], int bufb) {
#pragma unroll
    for (int n = 0; n < 4; ++n) {
      const int r = wn * 64 + (n << 4) + rl;
      const int rowb = bufb + 16384 + r * 64;
#pragma unroll
      for (int kk = 0; kk < 2; ++kk) {
        const int s = (qk + kk * 4) ^ (r & 7);
        b[n][kk] = *(const bf16x8*)&smem[rowb + s * 8];
      }
    }
  };

  const f32x4 zero = {0.f, 0.f, 0.f, 0.f};
  f32x4 acc[8][4];
#pragma unroll
  for (int m = 0; m < 8; ++m)
#pragma unroll
    for (int n = 0; n < 4; ++n) acc[m][n] = zero;

  // prologue: tile0 full + tile1 {B-lo, B-hi, A-lo}; drain tile0 (8 loads)
  STAGE(0, 0); STAGE(0, 1); STAGE(0, 2); STAGE(0, 3);
  STAGE(1, 0); STAGE(1, 1); STAGE(1, 2);
  asm volatile("s_waitcnt vmcnt(6)" ::: "memory");
  SCHED0;
  __builtin_amdgcn_s_barrier();
  SCHED0;

  for (int i = 0; i < NIT; ++i) {
    const int t0 = 2 * i;
    const bool notLast = (i + 1 < NIT);
    bf16x8 a2[2][2], bfr[4][2];

    // ---- K-tile t0 (buf0) ----
    LDBf(bfr, 0); LDA(a2, 0, 0); STAGE(t0 + 1, 3);       // ph1 (12 ds_reads)
    PH_SYNC; QUAD(0); PH_END;
    LDA(a2, 0, 1); STAGE(t0 + 2, 0);                     // ph2
    PH_SYNC; QUAD(1); PH_END;
    LDA(a2, 0, 2); STAGE(t0 + 2, 1);                     // ph3
    PH_SYNC; QUAD(2); PH_END;
    LDA(a2, 0, 3); STAGE(t0 + 2, 2);                     // ph4
    PH_SYNC_VM(notLast); QUAD(3); PH_END;

    // ---- K-tile t0+1 (buf1) ----
    LDBf(bfr, 32768); LDA(a2, 32768, 0); STAGE(t0 + 2, 3); // ph5 (12 ds_reads)
    PH_SYNC; QUAD(0); PH_END;
    LDA(a2, 32768, 1); STAGE(t0 + 3, 0);                 // ph6
    PH_SYNC; QUAD(1); PH_END;
    LDA(a2, 32768, 2); STAGE(t0 + 3, 1);                 // ph7
    PH_SYNC; QUAD(2); PH_END;
    LDA(a2, 32768, 3); STAGE(t0 + 3, 2);                 // ph8
    PH_SYNC_VM(notLast); QUAD(3); PH_END;
  }

  // epilogue: +bias, activation.  C/D map: col=lane&15, row=(lane>>4)*4+r
  const float* bp = segs.b[seg];
  const int act  = segs.act[seg];
  const int isBf = segs.bf16out[seg];
  u16*   opb = (u16*)segs.out[seg];
  float* opf = (float*)segs.out[seg];
  const int q4 = (lane >> 4) * 4;
  const int cl = lane & 15;
#pragma unroll
  for (int n = 0; n < 4; ++n) {
    int col = colBase + wn * 64 + n * 16 + cl;
    float bv = bp[col];
#pragma unroll
    for (int m = 0; m < 8; ++m) {
      int row = mBlock + wm * 128 + m * 16 + q4;
#pragma unroll
      for (int r = 0; r < 4; ++r) {
        float v = actf(acc[m][n][r] + bv, act);
        size_t idx = (size_t)(row + r) * (size_t)ldOut + col;
        if (isBf) opb[idx] = f2bf(v); else opf[idx] = v;
      }
    }
  }
}

// ---- 128x128 m97-structure kernel: kept for the two head GEMMs, whose
// grids would under-fill the chip at 256^2 tiles ----
__global__ __launch_bounds__(256, 2) void gemm_bt(
    const u16* __restrict__ A0, const u16* __restrict__ A1, int KA0, int K,
    SegArgs segs, int tileShift, int ldOut)
{
  __shared__ u16 As[BM * BK];
  __shared__ u16 Bs[BN * BK];

  const int tid  = threadIdx.x;
  const int lane = tid & 63;
  const int wave = tid >> 6;
  const int mBlock = blockIdx.x * BM;
  const int seg   = blockIdx.y >> tileShift;
  const int nTile = blockIdx.y & ((1 << tileShift) - 1);

  const u16* Wp = segs.W[seg];
  const int wm = wave & 1, wn = wave >> 1;

  const f32x4 zero = {0.f, 0.f, 0.f, 0.f};
  f32x4 acc[4][4];
#pragma unroll
  for (int i = 0; i < 4; ++i)
#pragma unroll
    for (int j = 0; j < 4; ++j) acc[i][j] = zero;

  for (int kb = 0; kb < K; kb += BK) {
    const u16* Aseg; int ka; int ldA;
    if (kb < KA0) { Aseg = A0; ka = kb;       ldA = KA0; }
    else          { Aseg = A1; ka = kb - KA0; ldA = K - KA0; }

#pragma unroll
    for (int it = 0; it < 4; ++it) {
      int s = it * 256 + tid;
      int m = s >> 3;
      int p = s & 7;
      int kc = p ^ (m & 7);
      const u16* srcA = Aseg + (size_t)(mBlock + m) * (size_t)ldA + (ka + kc * 8);
      const u16* srcB = Wp + (size_t)(nTile * BN + m) * (size_t)K + (kb + kc * 8);
      u16* dA = &As[(it * 256 + wave * 64) * 8];
      u16* dB = &Bs[(it * 256 + wave * 64) * 8];
      __builtin_amdgcn_global_load_lds((void*)srcA, (void*)dA, 16, 0, 0);
      __builtin_amdgcn_global_load_lds((void*)srcB, (void*)dB, 16, 0, 0);
    }
    __syncthreads();

#pragma unroll
    for (int ko = 0; ko < 2; ++ko) {
      bf16x8 af[4], bfr[4];
      int kcb = ko * 4 + (lane >> 4);
      int p = kcb ^ (lane & 7);
#pragma unroll
      for (int t = 0; t < 4; ++t) {
        int ml = wm * 64 + t * 16 + (lane & 15);
        af[t]  = *(const bf16x8*)&As[(ml * 8 + p) * 8];
        int nl = wn * 64 + t * 16 + (lane & 15);
        bfr[t] = *(const bf16x8*)&Bs[(nl * 8 + p) * 8];
      }
#pragma unroll
      for (int tm = 0; tm < 4; ++tm)
#pragma unroll
        for (int tn = 0; tn < 4; ++tn)
          acc[tm][tn] = __builtin_amdgcn_mfma_f32_16x16x32_bf16(af[tm], bfr[tn], acc[tm][tn], 0, 0, 0);
    }
    __syncthreads();
  }

  const float* bp = segs.b[seg];
  const int act = segs.act[seg];
  const int isBf = segs.bf16out[seg];
  u16*   opb = (u16*)segs.out[seg];
  float* opf = (float*)segs.out[seg];
  const int q  = lane >> 4;
  const int cl = lane & 15;
#pragma unroll
  for (int tn = 0; tn < 4; ++tn) {
    int col = nTile * BN + wn * 64 + tn * 16 + cl;
    float bv = bp[col];
#pragma unroll
    for (int tm = 0; tm < 4; ++tm) {
      int row = mBlock + wm * 64 + tm * 16 + q * 4;
#pragma unroll
      for (int r = 0; r < 4; ++r) {
        float v = actf(acc[tm][tn][r] + bv, act);
        size_t idx = (size_t)(row + r) * (size_t)ldOut + col;
        if (isBf) opb[idx] = f2bf(v); else opf[idx] = v;
      }
    }
  }
}

// combine gates (bf16): c_new = f*c0 + cand*i ; h_new = o*tanh(cand).
__global__ void lstm_ew(const u16* __restrict__ gates, const float* __restrict__ cold,
                        float* __restrict__ hout, float* __restrict__ cout,
                        u16* __restrict__ hb, int n)
{
  int i0 = (blockIdx.x * blockDim.x + threadIdx.x) * 8;
  if (i0 >= n) return;
  union U { uint4 v; u16 u[8]; };
  U F, I, C, O;
  F.v = *(const uint4*)(gates + i0);
  I.v = *(const uint4*)(gates + (size_t)n + i0);
  C.v = *(const uint4*)(gates + 2 * (size_t)n + i0);
  O.v = *(const uint4*)(gates + 3 * (size_t)n + i0);
  f32x8 c0v = *(const f32x8*)(cold + i0);
  f32x8 H, CN;
#pragma unroll
  for (int j = 0; j < 8; ++j) {
    float f  = bf2f(F.u[j]);
    float ig = bf2f(I.u[j]);
    float cd = bf2f(C.u[j]);   // already tanh'd, in (-1,1)
    float o  = bf2f(O.u[j]);
    float cn = f * c0v[j] + cd * ig;
    float e  = __expf(2.0f * cd);
    float th = (e - 1.0f) / (e + 1.0f);
    H[j]  = o * th;            // faithful double-tanh
    CN[j] = cn;
  }
  *(f32x8*)(hout + i0) = H;
  *(f32x8*)(cout + i0) = CN;
  *(uint4*)(hb + i0) = cvt8(H);
}

extern "C" void kernel_launch(void* const* d_in, const int* in_sizes, int n_in,
                              void* d_out, int out_size, void* d_ws, size_t ws_size,
                              hipStream_t stream)
{
  const size_t P   = 4096ull * 1024ull;  // 4,194,304 elements
  const size_t C2M = 2097152ull;         // cvt chunk = 2M elements

  const float* X   = (const float*)d_in[0];
  const float* h1i = (const float*)d_in[1];
  const float* h2i = (const float*)d_in[2];
  const float* c1i = (const float*)d_in[3];
  const float* c2i = (const float*)d_in[4];
  const float* Wf1 = (const float*)d_in[5];  const float* bf1_ = (const float*)d_in[6];
  const float* Wi1 = (const float*)d_in[7];  const float* bi1_ = (const float*)d_in[8];
  const float* Wc1 = (const float*)d_in[9];  const float* bc1_ = (const float*)d_in[10];
  const float* Wo1 = (const float*)d_in[11]; const float* bo1_ = (const float*)d_in[12];
  const float* Wf2 = (const float*)d_in[13]; const float* bf2_ = (const float*)d_in[14];
  const float* Wi2 = (const float*)d_in[15]; const float* bi2_ = (const float*)d_in[16];
  const float* Wc2 = (const float*)d_in[17]; const float* bc2_ = (const float*)d_in[18];
  const float* Wo2 = (const float*)d_in[19]; const float* bo2_ = (const float*)d_in[20];
  const float* W3  = (const float*)d_in[21]; const float* b3_  = (const float*)d_in[22];
  const float* W4  = (const float*)d_in[23]; const float* b4_  = (const float*)d_in[24];

  float* out = (float*)d_out;     // fp32 outputs (reference dtype)
  float* h1  = out + P;
  float* h2  = out + 2 * P;
  float* c1  = out + 3 * P;
  float* c2  = out + 4 * P;

  // ws layout (80 MB), phase-aliased:
  //  D @  0MB (32): gates bf16          (GEMM1->ew1, GEMM2->ew2)
  //  A @ 32MB (16): W1b -> W2b -> out3b
  //  B @ 48MB ( 8): Xb  -> h2ib
  //  Cg@ 56MB ( 8): h1ib -> h2b
  //  E @ 64MB ( 8): h1b
  //  F @ 72MB ( 8): W3b (4) + W4b (4)
  char* ws = (char*)d_ws;
  u16* gates = (u16*)ws;
  u16* Areg  = (u16*)(ws + (32ull << 20));
  u16* Breg  = (u16*)(ws + (48ull << 20));
  u16* Creg  = (u16*)(ws + (56ull << 20));
  u16* Ereg  = (u16*)(ws + (64ull << 20));
  u16* Freg  = (u16*)(ws + (72ull << 20));

  dim3 blk(256, 1, 1);
  dim3 blk2(512, 1, 1);

  // ---- cvtA: W1 gates, X, h1i, W3, W4 -> bf16 ----
  CvtArgs ca;
  ca.src[0]=Wf1;        ca.dst[0]=Areg;
  ca.src[1]=Wi1;        ca.dst[1]=Areg + C2M;
  ca.src[2]=Wc1;        ca.dst[2]=Areg + 2*C2M;
  ca.src[3]=Wo1;        ca.dst[3]=Areg + 3*C2M;
  ca.src[4]=X;          ca.dst[4]=Breg;
  ca.src[5]=X + C2M;    ca.dst[5]=Breg + C2M;
  ca.src[6]=h1i;        ca.dst[6]=Creg;
  ca.src[7]=h1i + C2M;  ca.dst[7]=Creg + C2M;
  ca.src[8]=W3;         ca.dst[8]=Freg;
  ca.src[9]=W4;         ca.dst[9]=Freg + C2M;
  cvt_f2b<<<dim3(1024, 10, 1), blk, 0, stream>>>(ca);

  // ---- LSTM layer 1: fused 4-gate GEMM (N=4096, K=2048), 8-phase 256^2 ----
  SegArgs s1;
  s1.W[0]=Areg; s1.W[1]=Areg+C2M; s1.W[2]=Areg+2*C2M; s1.W[3]=Areg+3*C2M;
  s1.b[0]=bf1_; s1.b[1]=bi1_; s1.b[2]=bc1_; s1.b[3]=bo1_;
  s1.out[0]=gates; s1.out[1]=gates+P; s1.out[2]=gates+2*P; s1.out[3]=gates+3*P;
  s1.act[0]=1; s1.act[1]=1; s1.act[2]=2; s1.act[3]=1;
  s1.bf16out[0]=s1.bf16out[1]=s1.bf16out[2]=s1.bf16out[3]=1;
  gemm8p<<<dim3(16,16,1), blk2, 0, stream>>>(Breg, Creg, 1024, 2048, s1, 2, 1024);
  lstm_ew<<<dim3(2048,1,1), blk, 0, stream>>>(gates, c1i, h1, c1, Ereg, (int)P);

  // ---- cvtB: W2 gates, h2i -> bf16 (overwrite A/B regions) ----
  CvtArgs cb;
  cb.src[0]=Wf2;        cb.dst[0]=Areg;
  cb.src[1]=Wi2;        cb.dst[1]=Areg + C2M;
  cb.src[2]=Wc2;        cb.dst[2]=Areg + 2*C2M;
  cb.src[3]=Wo2;        cb.dst[3]=Areg + 3*C2M;
  cb.src[4]=h2i;        cb.dst[4]=Breg;
  cb.src[5]=h2i + C2M;  cb.dst[5]=Breg + C2M;
  cvt_f2b<<<dim3(1024, 6, 1), blk, 0, stream>>>(cb);

  // ---- LSTM layer 2: A = [h1b | h2ib], 8-phase 256^2 ----
  SegArgs s2 = s1;
  s2.b[0]=bf2_; s2.b[1]=bi2_; s2.b[2]=bc2_; s2.b[3]=bo2_;
  gemm8p<<<dim3(16,16,1), blk2, 0, stream>>>(Ereg, Breg, 1024, 2048, s2, 2, 1024);
  lstm_ew<<<dim3(2048,1,1), blk, 0, stream>>>(gates, c2i, h2, c2, Creg, (int)P);

  // ---- head: out3b = relu(h2b @ W3^T + b3), N=2048, K=1024, bf16 out -> A ----
  SegArgs s3;
  for (int g = 0; g < 4; ++g) { s3.W[g]=Freg; s3.b[g]=b3_; s3.out[g]=Areg; s3.act[g]=3; s3.bf16out[g]=1; }
  gemm_bt<<<dim3(32,16,1), blk, 0, stream>>>(Creg, (const u16*)nullptr, 1024, 1024, s3, 4, 2048);

  // ---- head: out = out3b @ W4^T + b4, N=1024, K=2048, fp32 out ----
  SegArgs s4;
  for (int g = 0; g < 4; ++g) { s4.W[g]=Freg+C2M; s4.b[g]=b4_; s4.out[g]=out; s4.act[g]=0; s4.bf16out[g]=0; }
  gemm_bt<<<dim3(32,8,1), blk, 0, stream>>>(Areg, (const u16*)nullptr, 2048, 2048, s4, 3, 1024);
}